// Round 3
// baseline (82.651 us; speedup 1.0000x reference)
//
#include <hip/hip_runtime.h>

typedef __bf16 bf16;
typedef __bf16 bf16x4 __attribute__((ext_vector_type(4)));
typedef __bf16 bf16x8 __attribute__((ext_vector_type(8)));
typedef float f32x4 __attribute__((ext_vector_type(4)));

#define MFMA16(a, b, c) __builtin_amdgcn_mfma_f32_16x16x32_bf16(a, b, c, 0, 0, 0)

__device__ __forceinline__ void gload_lds16(const void* g, void* l) {
    __builtin_amdgcn_global_load_lds((const __attribute__((address_space(1))) void*)g,
                                     (__attribute__((address_space(3))) void*)l, 16, 0, 0);
}

__device__ __forceinline__ int clampi(int v, int lo, int hi) {
    return v < lo ? lo : (v > hi ? hi : v);
}

// ---------------- fp32 -> bf16 conversion (x, qkv_w, out_w) ----------------
__global__ void convert3(const float* __restrict__ x, const float* __restrict__ wq,
                         const float* __restrict__ wo,
                         bf16* __restrict__ xb, bf16* __restrict__ wqb, bf16* __restrict__ wob) {
    int u = blockIdx.x * 256 + threadIdx.x;
    const float4* src;
    bf16* dst;
    int off;
    if (u < 1048576) { src = (const float4*)x;  dst = xb;  off = u; }
    else if (u < 1048576 + 786432) { src = (const float4*)wq; dst = wqb; off = u - 1048576; }
    else { src = (const float4*)wo; dst = wob; off = u - (1048576 + 786432); }
    float4 v = src[off];
    bf16x4 o = { (bf16)v.x, (bf16)v.y, (bf16)v.z, (bf16)v.w };
    *(bf16x4*)(dst + (size_t)off * 4) = o;
}

// ---------------- QKV GEMM: 256x256 tile, 3-buf pipelined, counted vmcnt ----
// C[m][n] = sum_k A[m][k]*B[n][k] + bias[n], M=4096, N=3072, K=1024.
// 8 waves (2M x 4N), per-wave 128x64 (8x4 frags of 16x16x32). BK=32.
// LDS: 3 buffers x (A 16KB + B 16KB) = 96KB dynamic.
// LDS layout (A and B identical): pair-interleaved rows: line lrow (128B) holds
// rows {2*lrow, 2*lrow+1} x 32 k; 8 slots of 16B; physical slot = logical ^ (lrow&7).
// Epilogue: LDS-bounce per 128-row half -> coalesced q/k row stores + vT stores.
__global__ __launch_bounds__(512, 2) void gemm_qkv(
    const bf16* __restrict__ A, const bf16* __restrict__ B, const float* __restrict__ bias,
    bf16* __restrict__ qb, bf16* __restrict__ kb, bf16* __restrict__ vtb) {
    extern __shared__ char lds[];
    constexpr int K = 1024, NT = 32;
    const int tid = threadIdx.x;
    const int w = tid >> 6, lane = tid & 63;
    const int c = lane & 15, g = lane >> 4;
    const int wm = w >> 2, wn = w & 3;
    const int bn = blockIdx.x, bm = blockIdx.y;

    // bias first (oldest vmem ops -> retired by first counted wait)
    float bv[4];
#pragma unroll
    for (int ni = 0; ni < 4; ++ni) bv[ni] = bias[bn * 256 + wn * 64 + ni * 16 + c];

    // ---- staging source offsets (inverse-swizzled global, linear LDS dest) ----
    const int C0 = tid, C1 = tid + 512;
    auto srcoff = [&](int C) -> size_t {
        int lrow = C >> 3, sl = (C & 7) ^ (lrow & 7);
        int row = lrow * 2 + (sl >> 2);
        return (size_t)row * (K * 2) + (size_t)(sl & 3) * 16;
    };
    const char* aA0 = (const char*)A + (size_t)bm * 256 * K * 2 + srcoff(C0);
    const char* aA1 = (const char*)A + (size_t)bm * 256 * K * 2 + srcoff(C1);
    const char* aB0 = (const char*)B + (size_t)bn * 256 * K * 2 + srcoff(C0);
    const char* aB1 = (const char*)B + (size_t)bn * 256 * K * 2 + srcoff(C1);

    auto stageA = [&](int buf, int t) {
        char* dst = lds + buf * 32768;
        size_t ko = (size_t)t * 64;
        gload_lds16(aA0 + ko, dst + C0 * 16);
        gload_lds16(aA1 + ko, dst + C1 * 16);
    };
    auto stageB = [&](int buf, int t) {
        char* dst = lds + buf * 32768 + 16384;
        size_t ko = (size_t)t * 64;
        gload_lds16(aB0 + ko, dst + C0 * 16);
        gload_lds16(aB1 + ko, dst + C1 * 16);
    };

    // ---- fragment read offsets (swizzled) ----
    int aoff[8], boff[4];
#pragma unroll
    for (int mi = 0; mi < 8; ++mi) {
        int rl = wm * 128 + mi * 16 + c;
        int lr = rl >> 1;
        int sl = ((rl & 1) * 4 + g) ^ (lr & 7);
        aoff[mi] = lr * 128 + sl * 16;
    }
#pragma unroll
    for (int ni = 0; ni < 4; ++ni) {
        int rl = wn * 64 + ni * 16 + c;
        int lr = rl >> 1;
        int sl = ((rl & 1) * 4 + g) ^ (lr & 7);
        boff[ni] = 16384 + lr * 128 + sl * 16;
    }

    f32x4 acc[8][4] = {};

    // prologue: tiles 0 and 1
    stageA(0, 0); stageB(0, 0);
    stageA(1, 1); stageB(1, 1);

    int bufc = 0;
    for (int t = 0; t < NT; ++t) {
        int bufs = bufc + 2; if (bufs >= 3) bufs -= 3;
        if (t + 2 < NT) stageA(bufs, t + 2);
        if (t + 2 < NT)      asm volatile("s_waitcnt vmcnt(6)" ::: "memory");
        else if (t + 1 < NT) asm volatile("s_waitcnt vmcnt(4)" ::: "memory");
        else                 asm volatile("s_waitcnt vmcnt(0)" ::: "memory");
        __builtin_amdgcn_s_barrier();
        __builtin_amdgcn_sched_barrier(0);
        const char* base = lds + bufc * 32768;
        bf16x8 bfr[4], af[4];
#pragma unroll
        for (int ni = 0; ni < 4; ++ni) bfr[ni] = *(const bf16x8*)(base + boff[ni]);
#pragma unroll
        for (int mi = 0; mi < 4; ++mi) af[mi] = *(const bf16x8*)(base + aoff[mi]);
        __builtin_amdgcn_s_setprio(1);
#pragma unroll
        for (int mi = 0; mi < 4; ++mi)
#pragma unroll
            for (int ni = 0; ni < 4; ++ni)
                acc[mi][ni] = MFMA16(af[mi], bfr[ni], acc[mi][ni]);
        __builtin_amdgcn_s_setprio(0);
        __builtin_amdgcn_s_barrier();
        __builtin_amdgcn_sched_barrier(0);
        if (t + 2 < NT) stageB(bufs, t + 2);
#pragma unroll
        for (int mi = 0; mi < 4; ++mi) af[mi] = *(const bf16x8*)(base + aoff[mi + 4]);
        __builtin_amdgcn_s_setprio(1);
#pragma unroll
        for (int mi = 0; mi < 4; ++mi)
#pragma unroll
            for (int ni = 0; ni < 4; ++ni)
                acc[mi + 4][ni] = MFMA16(af[mi], bfr[ni], acc[mi + 4][ni]);
        __builtin_amdgcn_s_setprio(0);
        __builtin_amdgcn_s_barrier();
        __builtin_amdgcn_sched_barrier(0);
        bufc = bufc + 1 == 3 ? 0 : bufc + 1;
    }

    // ---- epilogue: LDS bounce in two 128-row halves ----
    const int b_idx = (bm * 256) >> 11;
    const int t0 = (bm * 256) & 2047;
    const int which = bn >> 2;               // 0:q 1:k 2:v
    const int hh = tid >> 7, idx = tid & 127;
    const int hab = (bn & 3) * 4 + hh;

#pragma unroll
    for (int H = 0; H < 2; ++H) {
        if (H) { __builtin_amdgcn_s_barrier(); __builtin_amdgcn_sched_barrier(0); }
        if (wm == H) {
            if (which == 2) {
#pragma unroll
                for (int mi = 0; mi < 8; ++mi)
#pragma unroll
                    for (int ni = 0; ni < 4; ++ni) {
                        int tl = mi * 16 + g * 4;
                        int d = ni * 16 + c;
                        f32x4 v = acc[mi][ni];
                        float bb = bv[ni];
                        bf16x4 pv = { (bf16)(v[0] + bb), (bf16)(v[1] + bb),
                                      (bf16)(v[2] + bb), (bf16)(v[3] + bb) };
                        *(bf16x4*)(lds + wn * 16384 + d * 256 + ((tl * 2) ^ ((d & 7) << 4))) = pv;
                    }
            } else {
#pragma unroll
                for (int mi = 0; mi < 8; ++mi)
#pragma unroll
                    for (int ni = 0; ni < 4; ++ni) {
                        int d = ni * 16 + c;
                        float bb = bv[ni];
#pragma unroll
                        for (int r = 0; r < 4; ++r) {
                            int tl = mi * 16 + g * 4 + r;
                            *(bf16*)(lds + wn * 16384 + tl * 128 + ((d * 2) ^ ((tl & 7) << 4))) =
                                (bf16)(acc[mi][ni][r] + bb);
                        }
                    }
            }
        }
        __builtin_amdgcn_s_barrier();
        __builtin_amdgcn_sched_barrier(0);
        if (which == 2) {
            size_t vbase = ((size_t)(b_idx * 16 + hab) * 64) * 2048 + t0 + H * 128;
#pragma unroll
            for (int j = 0; j < 8; ++j) {
                int d = j * 8 + (idx >> 4);
                bf16x8 vv = *(const bf16x8*)(lds + hh * 16384 + d * 256 +
                                             (((idx & 15) * 16) ^ ((d & 7) << 4)));
                *(bf16x8*)(vtb + vbase + (size_t)d * 2048 + (idx & 15) * 8) = vv;
            }
        } else {
            bf16* dst = (which ? kb : qb) +
                        ((size_t)(b_idx * 16 + hab) * 2048 + t0 + H * 128) * 64;
#pragma unroll
            for (int j = 0; j < 8; ++j) {
                int C2 = j * 128 + idx;
                int tt = C2 >> 3, sl = C2 & 7;
                bf16x8 vv = *(const bf16x8*)(lds + hh * 16384 + tt * 128 +
                                             ((sl * 16) ^ ((tt & 7) << 4)));
                *(bf16x8*)(dst + tt * 64 + sl * 8) = vv;
            }
        }
    }
}

// ---------------- bf16 GEMM (out-proj): C = A * B^T + bias, fp32 out -------
template <int NN>
__global__ __launch_bounds__(256, 2) void gemm_bt(
    const bf16* __restrict__ A, const bf16* __restrict__ B, const float* __restrict__ bias,
    float* __restrict__ outf) {
    constexpr int K = 1024;
    constexpr int KT = K / 32;
    __shared__ bf16 As[2][128 * 32];
    __shared__ bf16 Bs[2][128 * 32];
    const int tid = threadIdx.x;
    const int w = tid >> 6, lane = tid & 63;
    const int c = lane & 15, g = lane >> 4;
    const int wr = w >> 1, wc = w & 1;
    const int bn = blockIdx.x, bm = blockIdx.y;
    const size_t abase = (size_t)bm * 128 * K;
    const size_t bbase = (size_t)bn * 128 * K;

    f32x4 acc[4][4] = {};

    auto stage = [&](int buf, int k0) {
#pragma unroll
        for (int i = 0; i < 2; ++i) {
            int u = i * 256 + tid;
            const bf16* ga = A + abase + (size_t)(u >> 2) * K + k0 + (u & 3) * 8;
            gload_lds16(ga, &As[buf][(i * 256 + w * 64) * 8]);
            const bf16* gb = B + bbase + (size_t)(u >> 2) * K + k0 + (u & 3) * 8;
            gload_lds16(gb, &Bs[buf][(i * 256 + w * 64) * 8]);
        }
    };

    stage(0, 0);
    __syncthreads();
    int cur = 0;
    for (int kt = 0; kt < KT; ++kt) {
        if (kt + 1 < KT) stage(cur ^ 1, (kt + 1) * 32);
        bf16x8 af[4], bfr[4];
#pragma unroll
        for (int mi = 0; mi < 4; ++mi)
            af[mi] = *(const bf16x8*)&As[cur][(wr * 64 + mi * 16 + c) * 32 + g * 8];
#pragma unroll
        for (int ni = 0; ni < 4; ++ni)
            bfr[ni] = *(const bf16x8*)&Bs[cur][(wc * 64 + ni * 16 + c) * 32 + g * 8];
#pragma unroll
        for (int mi = 0; mi < 4; ++mi)
#pragma unroll
            for (int ni = 0; ni < 4; ++ni)
                acc[mi][ni] = MFMA16(af[mi], bfr[ni], acc[mi][ni]);
        __syncthreads();
        cur ^= 1;
    }

#pragma unroll
    for (int mi = 0; mi < 4; ++mi) {
        int m0 = bm * 128 + wr * 64 + mi * 16 + g * 4;
#pragma unroll
        for (int ni = 0; ni < 4; ++ni) {
            int n = bn * 128 + wc * 64 + ni * 16 + c;
            float bvv = bias[n];
            f32x4 v = acc[mi][ni];
#pragma unroll
            for (int r = 0; r < 4; ++r)
                outf[(size_t)(m0 + r) * NN + n] = v[r] + bvv;
        }
    }
}

// ---------------- windowed decay attention ---------------------------------
__global__ __launch_bounds__(256, 4) void attn_win(
    const bf16* __restrict__ qb, const bf16* __restrict__ kb,
    const bf16* __restrict__ vtb, const float* __restrict__ decay,
    bf16* __restrict__ ao) {
    __shared__ __attribute__((aligned(16))) char kp_buf[16384];
    __shared__ __attribute__((aligned(16))) char vt_buf[16384];
    const int tid = threadIdx.x;
    const int w = tid >> 6, lane = tid & 63;
    const int c = lane & 15, g = lane >> 4;
    const int phys = blockIdx.x;
    const int blk = (phys & 7) * 128 + (phys >> 3);
    const int qt = blk & 31, bh = blk >> 5;
    const int h = bh & 15, b = bh >> 4;
    const int q0 = qt * 64;
    const int ks = q0 - 32;
    const bf16* Q = qb + (size_t)bh * 2048 * 64;
    const char* Kg = (const char*)(kb + (size_t)bh * 2048 * 64);
    const char* Vg = (const char*)(vtb + (size_t)bh * 64 * 2048);
    const float alpha = log1pf(__expf(decay[h]));

#pragma unroll
    for (int i = 0; i < 4; ++i) {
        int u = i * 256 + tid;
        int r = u >> 3;
        int bb = ((u & 7) * 16) ^ ((r & 7) << 4);
        int t = clampi(ks + r, 0, 2047);
        gload_lds16(Kg + (size_t)t * 128 + bb, kp_buf + u * 16);
    }
#pragma unroll
    for (int i = 0; i < 4; ++i) {
        int u = i * 256 + tid;
        int d = u >> 4;
        int bb = ((u & 15) * 16) ^ ((d & 7) << 4);
        int kbyte = clampi(ks * 2 + bb, 0, 4080);
        gload_lds16(Vg + (size_t)d * 4096 + kbyte, vt_buf + u * 16);
    }

    bf16x8 qf[2];
#pragma unroll
    for (int dh = 0; dh < 2; ++dh)
        qf[dh] = *(const bf16x8*)(Q + (size_t)(q0 + w * 16 + c) * 64 + dh * 32 + g * 8);

    __syncthreads();

    f32x4 s[8] = {};
#pragma unroll
    for (int dh = 0; dh < 2; ++dh)
#pragma unroll
        for (int ki = 0; ki < 8; ++ki) {
            int r = ki * 16 + c;
            bf16x8 kf = *(const bf16x8*)(kp_buf + r * 128 +
                                         ((dh * 64 + g * 16) ^ ((r & 7) << 4)));
            s[ki] = MFMA16(kf, qf[dh], s[ki]);
        }

    const int tq = q0 + w * 16 + c;
    float mx = -1e30f;
#pragma unroll
    for (int ki = 0; ki < 8; ++ki)
#pragma unroll
        for (int r = 0; r < 4; ++r) {
            int tk = ks + ki * 16 + g * 4 + r;
            float val = (tk < 0 || tk > 2047)
                            ? -1e30f
                            : s[ki][r] * 0.125f - alpha * fabsf((float)(tq - tk));
            s[ki][r] = val;
            mx = fmaxf(mx, val);
        }
    mx = fmaxf(mx, __shfl_xor(mx, 16));
    mx = fmaxf(mx, __shfl_xor(mx, 32));
    float ls = 0.f;
#pragma unroll
    for (int ki = 0; ki < 8; ++ki)
#pragma unroll
        for (int r = 0; r < 4; ++r) {
            float p = __expf(s[ki][r] - mx);
            s[ki][r] = p;
            ls += p;
        }
    ls += __shfl_xor(ls, 16);
    ls += __shfl_xor(ls, 32);

    __syncthreads();

#pragma unroll
    for (int ki = 0; ki < 8; ++ki) {
        bf16x4 pv = { (bf16)s[ki][0], (bf16)s[ki][1], (bf16)s[ki][2], (bf16)s[ki][3] };
        *(bf16x4*)(kp_buf + (w * 16 + c) * 256 + ((ki * 32 + g * 8) ^ ((c & 7) << 4))) = pv;
    }
    asm volatile("s_waitcnt lgkmcnt(0)" ::: "memory");
    __builtin_amdgcn_sched_barrier(0);

    f32x4 o[4] = {};
#pragma unroll
    for (int kst = 0; kst < 4; ++kst) {
        bf16x8 pa = *(const bf16x8*)(kp_buf + (w * 16 + c) * 256 +
                                     ((kst * 64 + g * 16) ^ ((c & 7) << 4)));
#pragma unroll
        for (int nf = 0; nf < 4; ++nf) {
            int d = nf * 16 + c;
            bf16x8 vb = *(const bf16x8*)(vt_buf + d * 256 +
                                         ((kst * 64 + g * 16) ^ ((d & 7) << 4)));
            o[nf] = MFMA16(pa, vb, o[nf]);
        }
    }

    float lsum[4];
#pragma unroll
    for (int r = 0; r < 4; ++r) lsum[r] = __shfl(ls, g * 4 + r);

    char* Ob = kp_buf + w * 4096;
#pragma unroll
    for (int nf = 0; nf < 4; ++nf)
#pragma unroll
        for (int r = 0; r < 4; ++r) {
            int q = g * 4 + r;
            int d = nf * 16 + c;
            *(bf16*)(Ob + q * 128 + ((d * 2) ^ ((q & 7) << 4))) =
                (bf16)(o[nf][r] / lsum[r]);
        }
    asm volatile("s_waitcnt lgkmcnt(0)" ::: "memory");
    __builtin_amdgcn_sched_barrier(0);

    {
        int q = lane >> 2;
        int ch = lane & 3;
        int t = q0 + w * 16 + q;
        bf16* dst = ao + (size_t)(b * 2048 + t) * 1024 + h * 64 + ch * 16;
#pragma unroll
        for (int j = 0; j < 2; ++j) {
            bf16x8 v = *(const bf16x8*)(Ob + q * 128 + ((ch * 32 + j * 16) ^ ((q & 7) << 4)));
            *(bf16x8*)(dst + j * 8) = v;
        }
    }
}

// ---------------- launch ----------------------------------------------------
extern "C" void kernel_launch(void* const* d_in, const int* in_sizes, int n_in,
                              void* d_out, int out_size, void* d_ws, size_t ws_size,
                              hipStream_t stream) {
    const float* x = (const float*)d_in[0];
    const float* qkv_w = (const float*)d_in[1];
    const float* qkv_b = (const float*)d_in[2];
    const float* out_w = (const float*)d_in[3];
    const float* out_b = (const float*)d_in[4];
    const float* decay = (const float*)d_in[5];
    float* out = (float*)d_out;

    char* ws = (char*)d_ws;
    bf16* xb   = (bf16*)(ws);                       // 8 MB
    bf16* wqb  = (bf16*)(ws + 8388608);             // 6 MB
    bf16* wob  = (bf16*)(ws + 14680064);            // 2 MB
    bf16* qbuf = (bf16*)(ws + 16777216);            // 8 MB  [bh][t][64]
    bf16* kbuf = (bf16*)(ws + 25165824);            // 8 MB  [bh][t][64]
    bf16* vtb  = (bf16*)(ws + 33554432);            // 8 MB  [bh][64][t]
    bf16* aob  = (bf16*)(ws + 41943040);            // 8 MB  [4096][1024]

    hipFuncSetAttribute((const void*)gemm_qkv,
                        hipFuncAttributeMaxDynamicSharedMemorySize, 98304);

    convert3<<<dim3(8192), dim3(256), 0, stream>>>(x, qkv_w, out_w, xb, wqb, wob);
    gemm_qkv<<<dim3(12, 16), dim3(512), 98304, stream>>>(
        xb, wqb, qkv_b, qbuf, kbuf, vtb);
    attn_win<<<dim3(1024), dim3(256), 0, stream>>>(qbuf, kbuf, vtb, decay, aob);
    gemm_bt<1024><<<dim3(8, 32), dim3(256), 0, stream>>>(aob, wob, out_b, out);
}

// Round 4
// 73.325 us; speedup vs baseline: 1.1272x; 1.1272x over previous
//
#include <hip/hip_runtime.h>

typedef __bf16 bf16;
typedef __bf16 bf16x4 __attribute__((ext_vector_type(4)));
typedef __bf16 bf16x8 __attribute__((ext_vector_type(8)));
typedef float f32x4 __attribute__((ext_vector_type(4)));

#define MFMA16(a, b, c) __builtin_amdgcn_mfma_f32_16x16x32_bf16(a, b, c, 0, 0, 0)

__device__ __forceinline__ void gload_lds16(const void* g, void* l) {
    __builtin_amdgcn_global_load_lds((const __attribute__((address_space(1))) void*)g,
                                     (__attribute__((address_space(3))) void*)l, 16, 0, 0);
}

__device__ __forceinline__ int clampi(int v, int lo, int hi) {
    return v < lo ? lo : (v > hi ? hi : v);
}

// ---------------- fp32 -> bf16 conversion (x, qkv_w, out_w) ----------------
__global__ void convert3(const float* __restrict__ x, const float* __restrict__ wq,
                         const float* __restrict__ wo,
                         bf16* __restrict__ xb, bf16* __restrict__ wqb, bf16* __restrict__ wob) {
    int u = blockIdx.x * 256 + threadIdx.x;
    const float4* src;
    bf16* dst;
    int off;
    if (u < 1048576) { src = (const float4*)x;  dst = xb;  off = u; }
    else if (u < 1048576 + 786432) { src = (const float4*)wq; dst = wqb; off = u - 1048576; }
    else { src = (const float4*)wo; dst = wob; off = u - (1048576 + 786432); }
    float4 v = src[off];
    bf16x4 o = { (bf16)v.x, (bf16)v.y, (bf16)v.z, (bf16)v.w };
    *(bf16x4*)(dst + (size_t)off * 4) = o;
}

// ---------------- 128x128 GEMM, 3-buf counted-vmcnt pipeline ----------------
// C[m][n] = sum_k A[m][k]*B[n][k] + bias[n], K=1024, BK=32.
// 4 waves (2m x 2n), per-wave 64x64 (4x4 frags). LDS 3 x 16KB (A 8K + B 8K)
// -> 3 blocks/CU. Per K-tile: ds_reads issued BEFORE wait+barrier (m201
// order); stage tile t+2 (4 gloads); vmcnt(4) counted (never 0 till tail).
// LDS layout: line (128B) = 2 rows x 4 slots; phys slot = logical ^ (line&7);
// staging pre-inverse-swizzles the GLOBAL source, LDS dest linear (rule 21).
// EPI 0: LDS-bounce scatter -> q[bh][t][64], k[bh][t][64], vT[bh][64][t]
// EPI 1: direct fp32 epilogue -> outf[m][1024]
template <int EPI>
__global__ __launch_bounds__(256, 3) void gemm128(
    const bf16* __restrict__ A, const bf16* __restrict__ B, const float* __restrict__ bias,
    bf16* __restrict__ qb, bf16* __restrict__ kb, bf16* __restrict__ vtb,
    float* __restrict__ outf) {
    constexpr int K = 1024, NT = 32;
    __shared__ __attribute__((aligned(16))) char lds[49152];
    const int tid = threadIdx.x;
    const int w = tid >> 6, lane = tid & 63;
    const int c = lane & 15, g = lane >> 4;
    const int wm = w >> 1, wn = w & 1;
    const int bn = blockIdx.x, bm = blockIdx.y;

    float bv[4];
#pragma unroll
    for (int ni = 0; ni < 4; ++ni) bv[ni] = bias[bn * 128 + wn * 64 + ni * 16 + c];

    auto srcoff = [&](int C) -> size_t {
        int lrow = C >> 3, sl = (C & 7) ^ (lrow & 7);
        int row = lrow * 2 + (sl >> 2);
        return (size_t)row * (K * 2) + (size_t)(sl & 3) * 16;
    };
    const char* aA0 = (const char*)A + (size_t)bm * 128 * K * 2 + srcoff(tid);
    const char* aA1 = (const char*)A + (size_t)bm * 128 * K * 2 + srcoff(tid + 256);
    const char* aB0 = (const char*)B + (size_t)bn * 128 * K * 2 + srcoff(tid);
    const char* aB1 = (const char*)B + (size_t)bn * 128 * K * 2 + srcoff(tid + 256);

    auto stage = [&](int buf, int t) {
        char* d = lds + buf * 16384;
        size_t ko = (size_t)t * 64;
        gload_lds16(aA0 + ko, d + tid * 16);
        gload_lds16(aA1 + ko, d + (tid + 256) * 16);
        gload_lds16(aB0 + ko, d + 8192 + tid * 16);
        gload_lds16(aB1 + ko, d + 8192 + (tid + 256) * 16);
    };

    int aoff[4], boff[4];
#pragma unroll
    for (int i = 0; i < 4; ++i) {
        int rl = wm * 64 + i * 16 + c, lr = rl >> 1;
        int sl = ((rl & 1) * 4 + g) ^ (lr & 7);
        aoff[i] = lr * 128 + sl * 16;
        rl = wn * 64 + i * 16 + c; lr = rl >> 1;
        sl = ((rl & 1) * 4 + g) ^ (lr & 7);
        boff[i] = 8192 + lr * 128 + sl * 16;
    }

    f32x4 acc[4][4] = {};

    stage(0, 0); stage(1, 1);
    asm volatile("s_waitcnt vmcnt(4)" ::: "memory");  // tile 0 complete; tile 1 in flight
    __builtin_amdgcn_s_barrier();
    __builtin_amdgcn_sched_barrier(0);

    int bufc = 0;
    for (int t = 0; t < NT; ++t) {
        const char* base = lds + bufc * 16384;
        bf16x8 af[4], bfr[4];
#pragma unroll
        for (int ni = 0; ni < 4; ++ni) bfr[ni] = *(const bf16x8*)(base + boff[ni]);
#pragma unroll
        for (int mi = 0; mi < 4; ++mi) af[mi] = *(const bf16x8*)(base + aoff[mi]);
        if (t + 2 < NT) {
            int bufs = bufc + 2; if (bufs >= 3) bufs -= 3;
            stage(bufs, t + 2);
            asm volatile("s_waitcnt vmcnt(4)" ::: "memory");   // retire tile t+1
        } else if (t + 1 < NT) {
            asm volatile("s_waitcnt vmcnt(0)" ::: "memory");   // tail drain
        }
        __builtin_amdgcn_s_barrier();
        __builtin_amdgcn_sched_barrier(0);
        __builtin_amdgcn_s_setprio(1);
#pragma unroll
        for (int mi = 0; mi < 4; ++mi)
#pragma unroll
            for (int ni = 0; ni < 4; ++ni)
                acc[mi][ni] = MFMA16(af[mi], bfr[ni], acc[mi][ni]);
        __builtin_amdgcn_s_setprio(0);
        __builtin_amdgcn_s_barrier();
        __builtin_amdgcn_sched_barrier(0);
        bufc = bufc + 1 == 3 ? 0 : bufc + 1;
    }

    if constexpr (EPI == 0) {
        const int which = bn >> 3;          // 0:q 1:k 2:v
        const int hb = (bn & 7) * 2;
        const int b_ = bm >> 4;
        const int t0 = (bm & 15) * 128;
        if (which == 2) {
            // vT bounce: [d 0..127][256B of t], swizzled
#pragma unroll
            for (int mi = 0; mi < 4; ++mi)
#pragma unroll
                for (int ni = 0; ni < 4; ++ni) {
                    int d = wn * 64 + ni * 16 + c;
#pragma unroll
                    for (int r = 0; r < 4; ++r) {
                        int tl = wm * 64 + mi * 16 + g * 4 + r;
                        *(bf16*)(lds + d * 256 + ((tl * 2) ^ ((d & 7) << 4))) =
                            (bf16)(acc[mi][ni][r] + bv[ni]);
                    }
                }
            __syncthreads();
#pragma unroll
            for (int j = 0; j < 8; ++j) {
                int u = j * 256 + tid;
                int d = u >> 4, ck = u & 15;
                bf16x8 vv = *(const bf16x8*)(lds + d * 256 + ((ck * 16) ^ ((d & 7) << 4)));
                *(bf16x8*)(vtb + ((size_t)(b_ * 16 + hb + (d >> 6)) * 64 + (d & 63)) * 2048 +
                           t0 + ck * 8) = vv;
            }
        } else {
            // q/k bounce: [tl 0..127][256B of d], swizzled
#pragma unroll
            for (int mi = 0; mi < 4; ++mi)
#pragma unroll
                for (int ni = 0; ni < 4; ++ni) {
                    int d = wn * 64 + ni * 16 + c;
#pragma unroll
                    for (int r = 0; r < 4; ++r) {
                        int tl = wm * 64 + mi * 16 + g * 4 + r;
                        *(bf16*)(lds + tl * 256 + ((d * 2) ^ ((tl & 7) << 4))) =
                            (bf16)(acc[mi][ni][r] + bv[ni]);
                    }
                }
            __syncthreads();
            bf16* dst0 = which ? kb : qb;
#pragma unroll
            for (int j = 0; j < 8; ++j) {
                int u = j * 256 + tid;
                int tl = u >> 4, ck = u & 15;
                bf16x8 vv = *(const bf16x8*)(lds + tl * 256 + ((ck * 16) ^ ((tl & 7) << 4)));
                *(bf16x8*)(dst0 + ((size_t)(b_ * 16 + hb + (ck >> 3)) * 2048 + t0 + tl) * 64 +
                           (ck & 7) * 8) = vv;
            }
        }
    } else {
#pragma unroll
        for (int mi = 0; mi < 4; ++mi) {
            int m0 = bm * 128 + wm * 64 + mi * 16 + g * 4;
#pragma unroll
            for (int ni = 0; ni < 4; ++ni) {
                int n = bn * 128 + wn * 64 + ni * 16 + c;
#pragma unroll
                for (int r = 0; r < 4; ++r)
                    outf[(size_t)(m0 + r) * 1024 + n] = acc[mi][ni][r] + bv[ni];
            }
        }
    }
}

// ---------------- windowed decay attention ---------------------------------
__global__ __launch_bounds__(256, 4) void attn_win(
    const bf16* __restrict__ qb, const bf16* __restrict__ kb,
    const bf16* __restrict__ vtb, const float* __restrict__ decay,
    bf16* __restrict__ ao) {
    __shared__ __attribute__((aligned(16))) char kp_buf[16384];
    __shared__ __attribute__((aligned(16))) char vt_buf[16384];
    const int tid = threadIdx.x;
    const int w = tid >> 6, lane = tid & 63;
    const int c = lane & 15, g = lane >> 4;
    const int phys = blockIdx.x;
    const int blk = (phys & 7) * 128 + (phys >> 3);
    const int qt = blk & 31, bh = blk >> 5;
    const int h = bh & 15, b = bh >> 4;
    const int q0 = qt * 64;
    const int ks = q0 - 32;
    const bf16* Q = qb + (size_t)bh * 2048 * 64;
    const char* Kg = (const char*)(kb + (size_t)bh * 2048 * 64);
    const char* Vg = (const char*)(vtb + (size_t)bh * 64 * 2048);
    const float alpha = log1pf(__expf(decay[h]));

#pragma unroll
    for (int i = 0; i < 4; ++i) {
        int u = i * 256 + tid;
        int r = u >> 3;
        int bb = ((u & 7) * 16) ^ ((r & 7) << 4);
        int t = clampi(ks + r, 0, 2047);
        gload_lds16(Kg + (size_t)t * 128 + bb, kp_buf + u * 16);
    }
#pragma unroll
    for (int i = 0; i < 4; ++i) {
        int u = i * 256 + tid;
        int d = u >> 4;
        int bb = ((u & 15) * 16) ^ ((d & 7) << 4);
        int kbyte = clampi(ks * 2 + bb, 0, 4080);
        gload_lds16(Vg + (size_t)d * 4096 + kbyte, vt_buf + u * 16);
    }

    bf16x8 qf[2];
#pragma unroll
    for (int dh = 0; dh < 2; ++dh)
        qf[dh] = *(const bf16x8*)(Q + (size_t)(q0 + w * 16 + c) * 64 + dh * 32 + g * 8);

    __syncthreads();

    f32x4 s[8] = {};
#pragma unroll
    for (int dh = 0; dh < 2; ++dh)
#pragma unroll
        for (int ki = 0; ki < 8; ++ki) {
            int r = ki * 16 + c;
            bf16x8 kf = *(const bf16x8*)(kp_buf + r * 128 +
                                         ((dh * 64 + g * 16) ^ ((r & 7) << 4)));
            s[ki] = MFMA16(kf, qf[dh], s[ki]);
        }

    const int tq = q0 + w * 16 + c;
    float mx = -1e30f;
#pragma unroll
    for (int ki = 0; ki < 8; ++ki)
#pragma unroll
        for (int r = 0; r < 4; ++r) {
            int tk = ks + ki * 16 + g * 4 + r;
            float val = (tk < 0 || tk > 2047)
                            ? -1e30f
                            : s[ki][r] * 0.125f - alpha * fabsf((float)(tq - tk));
            s[ki][r] = val;
            mx = fmaxf(mx, val);
        }
    mx = fmaxf(mx, __shfl_xor(mx, 16));
    mx = fmaxf(mx, __shfl_xor(mx, 32));
    float ls = 0.f;
#pragma unroll
    for (int ki = 0; ki < 8; ++ki)
#pragma unroll
        for (int r = 0; r < 4; ++r) {
            float p = __expf(s[ki][r] - mx);
            s[ki][r] = p;
            ls += p;
        }
    ls += __shfl_xor(ls, 16);
    ls += __shfl_xor(ls, 32);

    __syncthreads();

#pragma unroll
    for (int ki = 0; ki < 8; ++ki) {
        bf16x4 pv = { (bf16)s[ki][0], (bf16)s[ki][1], (bf16)s[ki][2], (bf16)s[ki][3] };
        *(bf16x4*)(kp_buf + (w * 16 + c) * 256 + ((ki * 32 + g * 8) ^ ((c & 7) << 4))) = pv;
    }
    asm volatile("s_waitcnt lgkmcnt(0)" ::: "memory");
    __builtin_amdgcn_sched_barrier(0);

    f32x4 o[4] = {};
#pragma unroll
    for (int kst = 0; kst < 4; ++kst) {
        bf16x8 pa = *(const bf16x8*)(kp_buf + (w * 16 + c) * 256 +
                                     ((kst * 64 + g * 16) ^ ((c & 7) << 4)));
#pragma unroll
        for (int nf = 0; nf < 4; ++nf) {
            int d = nf * 16 + c;
            bf16x8 vb = *(const bf16x8*)(vt_buf + d * 256 +
                                         ((kst * 64 + g * 16) ^ ((d & 7) << 4)));
            o[nf] = MFMA16(pa, vb, o[nf]);
        }
    }

    float lsum[4];
#pragma unroll
    for (int r = 0; r < 4; ++r) lsum[r] = __shfl(ls, g * 4 + r);

    char* Ob = kp_buf + w * 4096;
#pragma unroll
    for (int nf = 0; nf < 4; ++nf)
#pragma unroll
        for (int r = 0; r < 4; ++r) {
            int q = g * 4 + r;
            int d = nf * 16 + c;
            *(bf16*)(Ob + q * 128 + ((d * 2) ^ ((q & 7) << 4))) =
                (bf16)(o[nf][r] / lsum[r]);
        }
    asm volatile("s_waitcnt lgkmcnt(0)" ::: "memory");
    __builtin_amdgcn_sched_barrier(0);

    {
        int q = lane >> 2;
        int ch = lane & 3;
        int t = q0 + w * 16 + q;
        bf16* dst = ao + (size_t)(b * 2048 + t) * 1024 + h * 64 + ch * 16;
#pragma unroll
        for (int j = 0; j < 2; ++j) {
            bf16x8 v = *(const bf16x8*)(Ob + q * 128 + ((ch * 32 + j * 16) ^ ((q & 7) << 4)));
            *(bf16x8*)(dst + j * 8) = v;
        }
    }
}

// ---------------- launch ----------------------------------------------------
extern "C" void kernel_launch(void* const* d_in, const int* in_sizes, int n_in,
                              void* d_out, int out_size, void* d_ws, size_t ws_size,
                              hipStream_t stream) {
    const float* x = (const float*)d_in[0];
    const float* qkv_w = (const float*)d_in[1];
    const float* qkv_b = (const float*)d_in[2];
    const float* out_w = (const float*)d_in[3];
    const float* out_b = (const float*)d_in[4];
    const float* decay = (const float*)d_in[5];
    float* out = (float*)d_out;

    char* ws = (char*)d_ws;
    bf16* xb   = (bf16*)(ws);                       // 8 MB
    bf16* wqb  = (bf16*)(ws + 8388608);             // 6 MB
    bf16* wob  = (bf16*)(ws + 14680064);            // 2 MB
    bf16* qbuf = (bf16*)(ws + 16777216);            // 8 MB  [bh][t][64]
    bf16* kbuf = (bf16*)(ws + 25165824);            // 8 MB  [bh][t][64]
    bf16* vtb  = (bf16*)(ws + 33554432);            // 8 MB  [bh][64][t]
    bf16* aob  = (bf16*)(ws + 41943040);            // 8 MB  [4096][1024]

    convert3<<<dim3(8192), dim3(256), 0, stream>>>(x, qkv_w, out_w, xb, wqb, wob);
    gemm128<0><<<dim3(24, 32), dim3(256), 0, stream>>>(
        xb, wqb, qkv_b, qbuf, kbuf, vtb, (float*)nullptr);
    attn_win<<<dim3(1024), dim3(256), 0, stream>>>(qbuf, kbuf, vtb, decay, aob);
    gemm128<1><<<dim3(8, 32), dim3(256), 0, stream>>>(
        aob, wob, out_b, (bf16*)nullptr, (bf16*)nullptr, (bf16*)nullptr, out);
}